// Round 10
// baseline (246.755 us; speedup 1.0000x reference)
//
#include <hip/hip_runtime.h>
#include <cstdint>
#include <cstddef>

#define CC   96
#define BB   32
#define HHn  112
#define WWn  112
#define HWn  (HHn*WWn)        // 12544
#define NPIX (BB*HWn)         // 401408
#define EPSf 1e-5f

typedef __attribute__((ext_vector_type(8))) short bf16x8;
typedef __attribute__((ext_vector_type(4))) float f32x4;

__device__ inline unsigned short f2bf(float f) {      // RNE f32 -> bf16
  unsigned u = __float_as_uint(f);
  return (unsigned short)((u + 0x7FFFu + ((u >> 16) & 1u)) >> 16);
}
__device__ inline float bf2f(unsigned short h) {
  return __uint_as_float(((unsigned)h) << 16);
}

// ---------------- w_mix f32[o][c] -> bf16[o][c] ----------------
__global__ __launch_bounds__(256) void k_prep(const float* __restrict__ w,
                                              unsigned short* __restrict__ wbf) {
  int i = blockIdx.x * 256 + threadIdx.x;
  if (i < CC * CC) wbf[i] = f2bf(w[i]);
}

// ---------------- depthwise 7x7 conv: global loads, 4px x 7row items --------
// Block = half of one (b,c) plane, 256 threads (224 active), NO LDS/barrier.
// q = tid/28 (7-row chunk within half), s = tid%28 (4-col strip).
// acc[7][4]; 3 float4 global loads per input row (L1/L2 serve the overlap).
// launch_bounds(256,6) caps VGPR ~85 -> ~24 waves/CU.
__global__ __launch_bounds__(256, 6) void k_conv(const float* __restrict__ x,
                                                 const float* __restrict__ hk,
                                                 unsigned short* __restrict__ feat) {
  int tid = threadIdx.x;
  int bid = blockIdx.x;                                     // 6144
  int plane = __builtin_amdgcn_readfirstlane(bid >> 1);     // (b*C+c)
  int half  = __builtin_amdgcn_readfirstlane(bid & 1);
  int c = plane % CC;
  const float* xp = x + (long)plane * HWn;
  unsigned short* fp = feat + (long)plane * HWn;

  // 49 weights -> SGPRs (uniform per block)
  float wk[49];
  const float* kc = hk + c * 49;
#pragma unroll
  for (int i = 0; i < 49; ++i)
    wk[i] = __uint_as_float(__builtin_amdgcn_readfirstlane(__float_as_uint(kc[i])));

  if (tid >= 224) return;            // no barriers in kernel -> safe

  int q = tid / 28;                  // 7-row chunk 0..7
  int s = tid % 28;                  // 4-col strip
  int cb = s * 4;                    // window cols cb-3..cb+6
  int qb = half * 56 + q * 7;        // first output row
  bool aok0 = (s > 0);
  bool cok0 = (s < 27);
  int offA = aok0 ? cb - 4 : 0;
  int offC = cok0 ? cb + 4 : cb;

  float acc[7][4];
#pragma unroll
  for (int i = 0; i < 7; ++i)
#pragma unroll
    for (int j = 0; j < 4; ++j) acc[i][j] = 0.f;

#pragma unroll
  for (int rr = 0; rr < 13; ++rr) {       // input rows qb-3 .. qb+9
    int r = qb + rr - 3;
    bool vok = ((unsigned)r < (unsigned)HHn);
    int rc = r < 0 ? 0 : (r > HHn - 1 ? HHn - 1 : r);
    const float* row = xp + rc * WWn;
    float4 A  = *(const float4*)(row + offA);
    float4 Bv = *(const float4*)(row + cb);
    float4 Cv = *(const float4*)(row + offC);
    bool aok = vok && aok0;
    bool cok = vok && cok0;
    float win[10];                        // win[w] = x col cb-3+w
    win[0] = aok ? A.y : 0.f;
    win[1] = aok ? A.z : 0.f;
    win[2] = aok ? A.w : 0.f;
    win[3] = vok ? Bv.x : 0.f;
    win[4] = vok ? Bv.y : 0.f;
    win[5] = vok ? Bv.z : 0.f;
    win[6] = vok ? Bv.w : 0.f;
    win[7] = cok ? Cv.x : 0.f;
    win[8] = cok ? Cv.y : 0.f;
    win[9] = cok ? Cv.z : 0.f;

#pragma unroll
    for (int kh = 0; kh < 7; ++kh) {
      if (rr >= kh && rr - kh <= 6) {
        const int slot = rr - kh;
#pragma unroll
        for (int kw = 0; kw < 7; ++kw) {
          float wv = wk[kh * 7 + kw];
#pragma unroll
          for (int j = 0; j < 4; ++j)
            acc[slot][j] = fmaf(win[j + kw], wv, acc[slot][j]);
        }
      }
    }

    if (rr >= 6) {                        // output row qb + rr-6 complete
      const int slot = rr - 6;
      unsigned short* orow = fp + (qb + slot) * WWn + cb;
      uint2 pk;
      pk.x = (unsigned)f2bf(acc[slot][0]) | ((unsigned)f2bf(acc[slot][1]) << 16);
      pk.y = (unsigned)f2bf(acc[slot][2]) | ((unsigned)f2bf(acc[slot][3]) << 16);
      *(uint2*)orow = pk;
    }
  }
}

// ------- MFMA mix (bf16) -> BN stats ONLY (no mixed store) -------
// Block = 256 px; staging + MFMA identical to the proven k_mix; epilogue is
// just the register-accumulated sum/sumsq reduction + atomics.
__global__ __launch_bounds__(256, 2) void k_stats(const unsigned short* __restrict__ feat,
                                                  const unsigned short* __restrict__ wbf,
                                                  float* __restrict__ ssum,
                                                  float* __restrict__ ssq) {
  __shared__ unsigned short flds[256 * 128];   // 64 KB
  __shared__ float lsum[CC], lsq[CC];

  int tid = threadIdx.x;
  int bid = blockIdx.x;
  int b = bid / 49, tile = bid % 49;
  int p0 = tile * 256;

  if (tid < CC) { lsum[tid] = 0.f; lsq[tid] = 0.f; }

  const unsigned short* fb = feat + (long)b * CC * HWn + p0;
  int u   = (tid >> 3) & 7;
  int v   = tid & 7;
  int wv  = tid >> 6;
  int pgl = wv * 8 + v;

  bf16x8 vals[12];
#pragma unroll
  for (int s = 0; s < 12; ++s) {
    int c = s * 8 + u;
    vals[s] = *(const bf16x8*)(fb + (long)c * HWn + pgl * 8);
  }
#pragma unroll
  for (int s = 0; s < 12; ++s) {
#pragma unroll
    for (int e = 0; e < 8; ++e) {
      int pl = pgl * 8 + e;
      int kp = (pl ^ (pl >> 3)) & 7;
      flds[pl * 128 + ((s ^ kp) << 3) + u] = (unsigned short)vals[s][e];
    }
  }

  int l = tid & 63;
  int lm = l & 15, lg = l >> 4;
  bf16x8 a[6][3];
#pragma unroll
  for (int mt = 0; mt < 6; ++mt)
#pragma unroll
    for (int kk = 0; kk < 3; ++kk)
      a[mt][kk] = *(const bf16x8*)(wbf + (mt * 16 + lm) * CC + kk * 32 + lg * 8);

  __syncthreads();

  f32x4 acc[6][4];
#pragma unroll
  for (int mt = 0; mt < 6; ++mt)
#pragma unroll
    for (int j = 0; j < 4; ++j) acc[mt][j] = (f32x4){0.f, 0.f, 0.f, 0.f};

#pragma unroll
  for (int j = 0; j < 4; ++j) {
    int pl = (wv * 4 + j) * 16 + lm;
    int kp = (pl ^ (pl >> 3)) & 7;
#pragma unroll
    for (int kk = 0; kk < 3; ++kk) {
      bf16x8 bfrag = *(const bf16x8*)(&flds[pl * 128 + (((kk * 4 + lg) ^ kp) << 3)]);
#pragma unroll
      for (int mt = 0; mt < 6; ++mt)
        acc[mt][j] = __builtin_amdgcn_mfma_f32_16x16x32_bf16(a[mt][kk], bfrag, acc[mt][j], 0, 0, 0);
    }
  }

  // ---- stats on raw f32 acc (matches bngelu's recomputation exactly) ----
#pragma unroll
  for (int mt = 0; mt < 6; ++mt) {
#pragma unroll
    for (int r = 0; r < 4; ++r) {
      int o = mt * 16 + lg * 4 + r;
      float s = 0.f, q = 0.f;
#pragma unroll
      for (int j = 0; j < 4; ++j) {
        float vv = acc[mt][j][r];
        s += vv; q += vv * vv;
      }
      s += __shfl_xor(s, 1); q += __shfl_xor(q, 1);
      s += __shfl_xor(s, 2); q += __shfl_xor(q, 2);
      s += __shfl_xor(s, 4); q += __shfl_xor(q, 4);
      s += __shfl_xor(s, 8); q += __shfl_xor(q, 8);
      if (lm == 0) { atomicAdd(&lsum[o], s); atomicAdd(&lsq[o], q); }
    }
  }
  __syncthreads();

  if (tid < CC) atomicAdd(&ssum[tid], lsum[tid]);
  else if (tid < 2 * CC) atomicAdd(&ssq[tid - CC], lsq[tid - CC]);
}

__global__ void k_finalize(const float* __restrict__ ssum,
                           const float* __restrict__ ssq,
                           float* __restrict__ meanv,
                           float* __restrict__ rstdv) {
  int o = threadIdx.x;
  if (o < CC) {
    float m = ssum[o] * (1.0f / NPIX);
    float v = ssq[o] * (1.0f / NPIX) - m * m;
    meanv[o] = m;
    rstdv[o] = 1.0f / sqrtf(v + EPSf);
  }
}

// ------- MFMA mix recompute + BN (affine=False) + exact GELU, f32 out -------
__global__ __launch_bounds__(256, 2) void k_bngelu(const unsigned short* __restrict__ feat,
                                                   const unsigned short* __restrict__ wbf,
                                                   const float* __restrict__ meanv,
                                                   const float* __restrict__ rstdv,
                                                   float* __restrict__ out) {
  __shared__ unsigned short flds[256 * 128];   // 64 KB
  __shared__ float smean[CC], srstd[CC];

  int tid = threadIdx.x;
  int bid = blockIdx.x;
  int b = bid / 49, tile = bid % 49;
  int p0 = tile * 256;

  if (tid < CC) { smean[tid] = meanv[tid]; srstd[tid] = rstdv[tid]; }

  const unsigned short* fb = feat + (long)b * CC * HWn + p0;
  int u   = (tid >> 3) & 7;
  int v   = tid & 7;
  int wv  = tid >> 6;
  int pgl = wv * 8 + v;

  bf16x8 vals[12];
#pragma unroll
  for (int s = 0; s < 12; ++s) {
    int c = s * 8 + u;
    vals[s] = *(const bf16x8*)(fb + (long)c * HWn + pgl * 8);
  }
#pragma unroll
  for (int s = 0; s < 12; ++s) {
#pragma unroll
    for (int e = 0; e < 8; ++e) {
      int pl = pgl * 8 + e;
      int kp = (pl ^ (pl >> 3)) & 7;
      flds[pl * 128 + ((s ^ kp) << 3) + u] = (unsigned short)vals[s][e];
    }
  }

  int l = tid & 63;
  int lm = l & 15, lg = l >> 4;
  bf16x8 a[6][3];
#pragma unroll
  for (int mt = 0; mt < 6; ++mt)
#pragma unroll
    for (int kk = 0; kk < 3; ++kk)
      a[mt][kk] = *(const bf16x8*)(wbf + (mt * 16 + lm) * CC + kk * 32 + lg * 8);

  __syncthreads();

  f32x4 acc[6][4];
#pragma unroll
  for (int mt = 0; mt < 6; ++mt)
#pragma unroll
    for (int j = 0; j < 4; ++j) acc[mt][j] = (f32x4){0.f, 0.f, 0.f, 0.f};

#pragma unroll
  for (int j = 0; j < 4; ++j) {
    int pl = (wv * 4 + j) * 16 + lm;
    int kp = (pl ^ (pl >> 3)) & 7;
#pragma unroll
    for (int kk = 0; kk < 3; ++kk) {
      bf16x8 bfrag = *(const bf16x8*)(&flds[pl * 128 + (((kk * 4 + lg) ^ kp) << 3)]);
#pragma unroll
      for (int mt = 0; mt < 6; ++mt)
        acc[mt][j] = __builtin_amdgcn_mfma_f32_16x16x32_bf16(a[mt][kk], bfrag, acc[mt][j], 0, 0, 0);
    }
  }

  // ---- BN + exact GELU + direct f32 stores (64B/16-lane segments) ----
  float* ob = out + (long)b * CC * HWn + p0;
#pragma unroll
  for (int mt = 0; mt < 6; ++mt) {
#pragma unroll
    for (int r = 0; r < 4; ++r) {
      int o = mt * 16 + lg * 4 + r;
      float m = smean[o], rs = srstd[o];
      float* orow = ob + (long)o * HWn + lm;
#pragma unroll
      for (int j = 0; j < 4; ++j) {
        float z = (acc[mt][j][r] - m) * rs;
        orow[(wv * 4 + j) * 16] = 0.5f * z * (1.0f + erff(z * 0.70710678f));
      }
    }
  }
}

extern "C" void kernel_launch(void* const* d_in, const int* in_sizes, int n_in,
                              void* d_out, int out_size, void* d_ws, size_t ws_size,
                              hipStream_t stream) {
  const float* hk   = (const float*)d_in[0];   // local_hk [96,1,7,7]
  const float* x    = (const float*)d_in[1];   // x [32,96,112,112]
  const float* wmix = (const float*)d_in[2];   // w_mix [96,96]
  const float* bmix = (const float*)d_in[3];   // b_mix [96] (cancels in BN)
  (void)bmix;
  float* out = (float*)d_out;

  char* ws = (char*)d_ws;
  float* stats = (float*)ws;                           // sum,ssq,mean,rstd [96] each
  unsigned short* wbf    = (unsigned short*)(ws + 2048);     // 18432 B
  unsigned short* featbf = (unsigned short*)(ws + 32768);    // 77,070,336 B

  hipMemsetAsync(stats, 0, 768, stream);       // zero sum+ssq each call

  k_prep<<<36, 256, 0, stream>>>(wmix, wbf);
  k_conv<<<6144, 256, 0, stream>>>(x, hk, featbf);
  k_stats<<<1568, 256, 0, stream>>>(featbf, wbf, stats, stats + 96);
  k_finalize<<<1, 128, 0, stream>>>(stats, stats + 96, stats + 192, stats + 288);
  k_bngelu<<<1568, 256, 0, stream>>>(featbf, wbf, stats + 192, stats + 288, out);
}

// Round 11
// 228.354 us; speedup vs baseline: 1.0806x; 1.0806x over previous
//
#include <hip/hip_runtime.h>
#include <cstdint>
#include <cstddef>

#define CC   96
#define BB   32
#define HHn  112
#define WWn  112
#define HWn  (HHn*WWn)        // 12544
#define NPIX (BB*HWn)         // 401408
#define EPSf 1e-5f

typedef __attribute__((ext_vector_type(8))) short bf16x8;
typedef __attribute__((ext_vector_type(4))) float f32x4;

__device__ inline unsigned short f2bf(float f) {      // RNE f32 -> bf16
  unsigned u = __float_as_uint(f);
  return (unsigned short)((u + 0x7FFFu + ((u >> 16) & 1u)) >> 16);
}
__device__ inline float bf2f(unsigned short h) {
  return __uint_as_float(((unsigned)h) << 16);
}

// ---------------- w_mix f32[o][c] -> bf16[o][c] ----------------
__global__ __launch_bounds__(256) void k_prep(const float* __restrict__ w,
                                              unsigned short* __restrict__ wbf) {
  int i = blockIdx.x * 256 + threadIdx.x;
  if (i < CC * CC) wbf[i] = f2bf(w[i]);
}

// ---------------- depthwise 7x7 conv: global loads, 4px x 7row items --------
// Block = half of one (b,c) plane, 256 threads (224 active), NO LDS/barrier.
// acc[7][4]; 3 float4 global loads per input row (L1/L2 serve the overlap).
__global__ __launch_bounds__(256, 6) void k_conv(const float* __restrict__ x,
                                                 const float* __restrict__ hk,
                                                 unsigned short* __restrict__ feat) {
  int tid = threadIdx.x;
  int bid = blockIdx.x;                                     // 6144
  int plane = __builtin_amdgcn_readfirstlane(bid >> 1);     // (b*C+c)
  int half  = __builtin_amdgcn_readfirstlane(bid & 1);
  int c = plane % CC;
  const float* xp = x + (long)plane * HWn;
  unsigned short* fp = feat + (long)plane * HWn;

  // 49 weights -> SGPRs (uniform per block)
  float wk[49];
  const float* kc = hk + c * 49;
#pragma unroll
  for (int i = 0; i < 49; ++i)
    wk[i] = __uint_as_float(__builtin_amdgcn_readfirstlane(__float_as_uint(kc[i])));

  if (tid >= 224) return;            // no barriers in kernel -> safe

  int q = tid / 28;                  // 7-row chunk 0..7
  int s = tid % 28;                  // 4-col strip
  int cb = s * 4;                    // window cols cb-3..cb+6
  int qb = half * 56 + q * 7;        // first output row
  bool aok0 = (s > 0);
  bool cok0 = (s < 27);
  int offA = aok0 ? cb - 4 : 0;
  int offC = cok0 ? cb + 4 : cb;

  float acc[7][4];
#pragma unroll
  for (int i = 0; i < 7; ++i)
#pragma unroll
    for (int j = 0; j < 4; ++j) acc[i][j] = 0.f;

#pragma unroll
  for (int rr = 0; rr < 13; ++rr) {       // input rows qb-3 .. qb+9
    int r = qb + rr - 3;
    bool vok = ((unsigned)r < (unsigned)HHn);
    int rc = r < 0 ? 0 : (r > HHn - 1 ? HHn - 1 : r);
    const float* row = xp + rc * WWn;
    float4 A  = *(const float4*)(row + offA);
    float4 Bv = *(const float4*)(row + cb);
    float4 Cv = *(const float4*)(row + offC);
    bool aok = vok && aok0;
    bool cok = vok && cok0;
    float win[10];                        // win[w] = x col cb-3+w
    win[0] = aok ? A.y : 0.f;
    win[1] = aok ? A.z : 0.f;
    win[2] = aok ? A.w : 0.f;
    win[3] = vok ? Bv.x : 0.f;
    win[4] = vok ? Bv.y : 0.f;
    win[5] = vok ? Bv.z : 0.f;
    win[6] = vok ? Bv.w : 0.f;
    win[7] = cok ? Cv.x : 0.f;
    win[8] = cok ? Cv.y : 0.f;
    win[9] = cok ? Cv.z : 0.f;

#pragma unroll
    for (int kh = 0; kh < 7; ++kh) {
      if (rr >= kh && rr - kh <= 6) {
        const int slot = rr - kh;
#pragma unroll
        for (int kw = 0; kw < 7; ++kw) {
          float wv = wk[kh * 7 + kw];
#pragma unroll
          for (int j = 0; j < 4; ++j)
            acc[slot][j] = fmaf(win[j + kw], wv, acc[slot][j]);
        }
      }
    }

    if (rr >= 6) {                        // output row qb + rr-6 complete
      const int slot = rr - 6;
      unsigned short* orow = fp + (qb + slot) * WWn + cb;
      uint2 pk;
      pk.x = (unsigned)f2bf(acc[slot][0]) | ((unsigned)f2bf(acc[slot][1]) << 16);
      pk.y = (unsigned)f2bf(acc[slot][2]) | ((unsigned)f2bf(acc[slot][3]) << 16);
      *(uint2*)orow = pk;
    }
  }
}

// ------- MFMA 1x1 mix (bf16) + fused BN stats, 256 px/block -------
__global__ __launch_bounds__(256, 2) void k_mix(const unsigned short* __restrict__ feat,
                                                const unsigned short* __restrict__ wbf,
                                                unsigned short* __restrict__ mixed,
                                                float* __restrict__ ssum,
                                                float* __restrict__ ssq) {
  __shared__ unsigned short flds[256 * 128];   // 64 KB; reused for out-transpose
  __shared__ float lsum[CC], lsq[CC];

  int tid = threadIdx.x;
  int bid = blockIdx.x;
  int b = bid / 49, tile = bid % 49;
  int p0 = tile * 256;

  if (tid < CC) { lsum[tid] = 0.f; lsq[tid] = 0.f; }

  const unsigned short* fb = feat + (long)b * CC * HWn + p0;
  int u   = (tid >> 3) & 7;        // c within group of 8
  int v   = tid & 7;               // pixel-group low
  int wv  = tid >> 6;              // wave 0..3
  int pgl = wv * 8 + v;            // pixel-group 0..31 (8 px each)

  bf16x8 vals[12];
#pragma unroll
  for (int s = 0; s < 12; ++s) {
    int c = s * 8 + u;
    vals[s] = *(const bf16x8*)(fb + (long)c * HWn + pgl * 8);
  }
#pragma unroll
  for (int s = 0; s < 12; ++s) {
#pragma unroll
    for (int e = 0; e < 8; ++e) {
      int pl = pgl * 8 + e;
      int kp = (pl ^ (pl >> 3)) & 7;
      flds[pl * 128 + ((s ^ kp) << 3) + u] = (unsigned short)vals[s][e];
    }
  }

  int l = tid & 63;
  int lm = l & 15, lg = l >> 4;
  bf16x8 a[6][3];
#pragma unroll
  for (int mt = 0; mt < 6; ++mt)
#pragma unroll
    for (int kk = 0; kk < 3; ++kk)
      a[mt][kk] = *(const bf16x8*)(wbf + (mt * 16 + lm) * CC + kk * 32 + lg * 8);

  __syncthreads();

  f32x4 acc[6][4];
#pragma unroll
  for (int mt = 0; mt < 6; ++mt)
#pragma unroll
    for (int j = 0; j < 4; ++j) acc[mt][j] = (f32x4){0.f, 0.f, 0.f, 0.f};

#pragma unroll
  for (int j = 0; j < 4; ++j) {
    int pl = (wv * 4 + j) * 16 + lm;
    int kp = (pl ^ (pl >> 3)) & 7;
#pragma unroll
    for (int kk = 0; kk < 3; ++kk) {
      bf16x8 bfrag = *(const bf16x8*)(&flds[pl * 128 + (((kk * 4 + lg) ^ kp) << 3)]);
#pragma unroll
      for (int mt = 0; mt < 6; ++mt)
        acc[mt][j] = __builtin_amdgcn_mfma_f32_16x16x32_bf16(a[mt][kk], bfrag, acc[mt][j], 0, 0, 0);
    }
  }

  __syncthreads();   // staging reads complete; reuse flds as [o][px'] u16

#pragma unroll
  for (int mt = 0; mt < 6; ++mt) {
#pragma unroll
    for (int r = 0; r < 4; ++r) {
      int o = mt * 16 + lg * 4 + r;          // (o>>2)&3 == lg
      float s = 0.f, q = 0.f;
#pragma unroll
      for (int j = 0; j < 4; ++j) {
        unsigned short h = f2bf(acc[mt][j][r]);
        float vv = bf2f(h);
        int px = (wv * 4 + j) * 16 + lm;
        flds[o * 256 + (px ^ (lg << 4))] = h;
        s += vv; q += vv * vv;
      }
      s += __shfl_xor(s, 1); q += __shfl_xor(q, 1);
      s += __shfl_xor(s, 2); q += __shfl_xor(q, 2);
      s += __shfl_xor(s, 4); q += __shfl_xor(q, 4);
      s += __shfl_xor(s, 8); q += __shfl_xor(q, 8);
      if (lm == 0) { atomicAdd(&lsum[o], s); atomicAdd(&lsq[o], q); }
    }
  }
  __syncthreads();

  unsigned short* mbase = mixed + (long)b * CC * HWn + p0;
  int o2 = tid >> 5;          // 0..7
  int pxg = tid & 31;         // 8-px group
#pragma unroll
  for (int i = 0; i < 12; ++i) {
    int o = i * 8 + o2;
    int key = (o >> 2) & 3;
    uint4 vv = *(const uint4*)(&flds[o * 256 + ((pxg * 8) ^ (key << 4))]);
    *(uint4*)(mbase + (long)o * HWn + pxg * 8) = vv;
  }

  if (tid < CC) atomicAdd(&ssum[tid], lsum[tid]);
  else if (tid < 2 * CC) atomicAdd(&ssq[tid - CC], lsq[tid - CC]);
}

__global__ void k_finalize(const float* __restrict__ ssum,
                           const float* __restrict__ ssq,
                           float* __restrict__ meanv,
                           float* __restrict__ rstdv) {
  int o = threadIdx.x;
  if (o < CC) {
    float m = ssum[o] * (1.0f / NPIX);
    float v = ssq[o] * (1.0f / NPIX) - m * m;
    meanv[o] = m;
    rstdv[o] = 1.0f / sqrtf(v + EPSf);
  }
}

// ---------------- BN (affine=False) + exact GELU, bf16 in / f32 out --------
__global__ __launch_bounds__(256) void k_bngelu(const unsigned short* __restrict__ mixed,
                                                const float* __restrict__ meanv,
                                                const float* __restrict__ rstdv,
                                                float* __restrict__ out) {
  long e = ((long)blockIdx.x * 256 + threadIdx.x) * 8;
  int o = (int)((e / HWn) % CC);       // 12544 % 8 == 0 -> same plane
  float m = meanv[o], r = rstdv[o];
  bf16x8 v = *(const bf16x8*)(mixed + e);
  float4 g0, g1;
  float z;
  z = (bf2f((unsigned short)v[0]) - m) * r; g0.x = 0.5f * z * (1.0f + erff(z * 0.70710678f));
  z = (bf2f((unsigned short)v[1]) - m) * r; g0.y = 0.5f * z * (1.0f + erff(z * 0.70710678f));
  z = (bf2f((unsigned short)v[2]) - m) * r; g0.z = 0.5f * z * (1.0f + erff(z * 0.70710678f));
  z = (bf2f((unsigned short)v[3]) - m) * r; g0.w = 0.5f * z * (1.0f + erff(z * 0.70710678f));
  z = (bf2f((unsigned short)v[4]) - m) * r; g1.x = 0.5f * z * (1.0f + erff(z * 0.70710678f));
  z = (bf2f((unsigned short)v[5]) - m) * r; g1.y = 0.5f * z * (1.0f + erff(z * 0.70710678f));
  z = (bf2f((unsigned short)v[6]) - m) * r; g1.z = 0.5f * z * (1.0f + erff(z * 0.70710678f));
  z = (bf2f((unsigned short)v[7]) - m) * r; g1.w = 0.5f * z * (1.0f + erff(z * 0.70710678f));
  *(float4*)(out + e)     = g0;
  *(float4*)(out + e + 4) = g1;
}

extern "C" void kernel_launch(void* const* d_in, const int* in_sizes, int n_in,
                              void* d_out, int out_size, void* d_ws, size_t ws_size,
                              hipStream_t stream) {
  const float* hk   = (const float*)d_in[0];   // local_hk [96,1,7,7]
  const float* x    = (const float*)d_in[1];   // x [32,96,112,112]
  const float* wmix = (const float*)d_in[2];   // w_mix [96,96]
  const float* bmix = (const float*)d_in[3];   // b_mix [96] (cancels in BN)
  (void)bmix;
  float* out = (float*)d_out;

  char* ws = (char*)d_ws;
  float* stats = (float*)ws;                           // sum,ssq,mean,rstd [96] each
  unsigned short* wbf     = (unsigned short*)(ws + 2048);            // 18432 B
  unsigned short* featbf  = (unsigned short*)(ws + 32768);           // 77,070,336 B
  unsigned short* mixedbf = (unsigned short*)(ws + 32768 + 77070336);

  hipMemsetAsync(stats, 0, 768, stream);       // zero sum+ssq each call

  k_prep<<<36, 256, 0, stream>>>(wmix, wbf);
  k_conv<<<6144, 256, 0, stream>>>(x, hk, featbf);
  k_mix<<<1568, 256, 0, stream>>>(featbf, wbf, mixedbf, stats, stats + 96);
  k_finalize<<<1, 128, 0, stream>>>(stats, stats + 96, stats + 192, stats + 288);
  k_bngelu<<<18816, 256, 0, stream>>>(mixedbf, stats + 192, stats + 288, out);
}

// Round 12
// 207.779 us; speedup vs baseline: 1.1876x; 1.0990x over previous
//
#include <hip/hip_runtime.h>
#include <cstdint>
#include <cstddef>

#define CC   96
#define BB   32
#define HHn  112
#define WWn  112
#define HWn  (HHn*WWn)        // 12544
#define NPIX (BB*HWn)         // 401408
#define EPSf 1e-5f

typedef __attribute__((ext_vector_type(8))) short bf16x8;
typedef __attribute__((ext_vector_type(4))) float f32x4;

__device__ inline unsigned short f2bf(float f) {      // RNE f32 -> bf16
  unsigned u = __float_as_uint(f);
  return (unsigned short)((u + 0x7FFFu + ((u >> 16) & 1u)) >> 16);
}
__device__ inline float bf2f(unsigned short h) {
  return __uint_as_float(((unsigned)h) << 16);
}
__device__ inline float bflo(unsigned u) { return __uint_as_float(u << 16); }
__device__ inline float bfhi(unsigned u) { return __uint_as_float(u & 0xffff0000u); }

// ---------------- w_mix f32[o][c] -> bf16[o][c] ----------------
__global__ __launch_bounds__(256) void k_prep(const float* __restrict__ w,
                                              unsigned short* __restrict__ wbf) {
  int i = blockIdx.x * 256 + threadIdx.x;
  if (i < CC * CC) wbf[i] = f2bf(w[i]);
}

// ---------------- depthwise 7x7 conv: bf16 LDS half-plane ----------------
// Block = half of one (b,c) plane (56 output rows), 256 threads.
// Stage rows r0-3..r0+58 (62) as bf16 (13.9 KB LDS) -> 32 waves/CU capacity.
// Item (224 active): q=tid/28 (7-row chunk), s=tid%28 (4-col strip).
// Per input row: 3x ds_read_b64 (12 bf16), unpack, 7x7x4 FMA (f32 weights).
__global__ __launch_bounds__(256, 8) void k_conv(const float* __restrict__ x,
                                                 const float* __restrict__ hk,
                                                 unsigned short* __restrict__ feat) {
  __shared__ unsigned short lpl[62 * 112];   // 13,888 B

  int tid = threadIdx.x;
  int bid = blockIdx.x;                                     // 6144
  int plane = __builtin_amdgcn_readfirstlane(bid >> 1);     // (b*C+c)
  int half  = __builtin_amdgcn_readfirstlane(bid & 1);
  int c = plane % CC;
  int r0 = half * 56;                   // first output row of this half
  const float* xp = x + (long)plane * HWn;
  unsigned short* fp = feat + (long)plane * HWn;

  // ---- stage 62 rows (row-clamped) f32 -> bf16: 1736 float4 ----
#pragma unroll
  for (int it = 0; it < 7; ++it) {
    int idx = it * 256 + tid;
    if (idx < 1736) {
      int rl = idx / 28;                // local row 0..61
      int c4 = idx % 28;
      int g = r0 - 3 + rl;
      int gc = g < 0 ? 0 : (g > HHn - 1 ? HHn - 1 : g);
      float4 v = *(const float4*)(xp + gc * WWn + c4 * 4);
      uint2 pk;
      pk.x = (unsigned)f2bf(v.x) | ((unsigned)f2bf(v.y) << 16);
      pk.y = (unsigned)f2bf(v.z) | ((unsigned)f2bf(v.w) << 16);
      *(uint2*)(&lpl[rl * WWn + c4 * 4]) = pk;
    }
  }

  // 49 weights -> SGPRs (uniform per block)
  float wk[49];
  const float* kc = hk + c * 49;
#pragma unroll
  for (int i = 0; i < 49; ++i)
    wk[i] = __uint_as_float(__builtin_amdgcn_readfirstlane(__float_as_uint(kc[i])));

  __syncthreads();
  if (tid >= 224) return;

  int q = tid / 28;                  // 7-row chunk 0..7
  int s = tid % 28;                  // 4-col strip
  int cb = s * 4;                    // window cols cb-3..cb+6
  int qb_l = q * 7;                  // local output-row base (LDS row qb_l+rr)
  bool aok0 = (s > 0);
  bool cok0 = (s < 27);
  int e0 = aok0 ? cb - 4 : 0;        // first b64 elem offset (clamped)
  int e2 = cok0 ? cb + 4 : cb;       // last  b64 elem offset (clamped)

  float acc[7][4];
#pragma unroll
  for (int i = 0; i < 7; ++i)
#pragma unroll
    for (int j = 0; j < 4; ++j) acc[i][j] = 0.f;

#pragma unroll
  for (int rr = 0; rr < 13; ++rr) {       // input rows (global) r0+qb_l+rr-3
    int g = r0 + qb_l + rr - 3;
    bool vok = ((unsigned)g < (unsigned)HHn);
    const unsigned short* rowp = &lpl[(qb_l + rr) * WWn];
    uint2 U0 = *(const uint2*)(rowp + e0);   // cols cb-4..cb-1
    uint2 U1 = *(const uint2*)(rowp + cb);   // cols cb  ..cb+3
    uint2 U2 = *(const uint2*)(rowp + e2);   // cols cb+4..cb+7
    if (!(vok && aok0)) { U0.x = 0u; U0.y = 0u; }
    if (!vok)           { U1.x = 0u; U1.y = 0u; }
    if (!(vok && cok0)) { U2.x = 0u; U2.y = 0u; }

    float win[12];                    // win[w] = x col cb-4+w
    win[0]  = bflo(U0.x); win[1]  = bfhi(U0.x);
    win[2]  = bflo(U0.y); win[3]  = bfhi(U0.y);
    win[4]  = bflo(U1.x); win[5]  = bfhi(U1.x);
    win[6]  = bflo(U1.y); win[7]  = bfhi(U1.y);
    win[8]  = bflo(U2.x); win[9]  = bfhi(U2.x);
    win[10] = bflo(U2.y); win[11] = bfhi(U2.y);

    // input row rr feeds output slot = rr-kh (compile-time indices)
#pragma unroll
    for (int kh = 0; kh < 7; ++kh) {
      if (rr >= kh && rr - kh <= 6) {
        const int slot = rr - kh;
#pragma unroll
        for (int kw = 0; kw < 7; ++kw) {
          float wv = wk[kh * 7 + kw];
#pragma unroll
          for (int j = 0; j < 4; ++j)
            acc[slot][j] = fmaf(win[1 + kw + j], wv, acc[slot][j]);
        }
      }
    }

    if (rr >= 6) {                        // output row complete
      const int slot = rr - 6;
      unsigned short* orow = fp + (r0 + qb_l + slot) * WWn + cb;
      uint2 pk;
      pk.x = (unsigned)f2bf(acc[slot][0]) | ((unsigned)f2bf(acc[slot][1]) << 16);
      pk.y = (unsigned)f2bf(acc[slot][2]) | ((unsigned)f2bf(acc[slot][3]) << 16);
      *(uint2*)orow = pk;
    }
  }
}

// ------- MFMA 1x1 mix (bf16) + fused BN stats, 256 px/block -------
__global__ __launch_bounds__(256, 2) void k_mix(const unsigned short* __restrict__ feat,
                                                const unsigned short* __restrict__ wbf,
                                                unsigned short* __restrict__ mixed,
                                                float* __restrict__ ssum,
                                                float* __restrict__ ssq) {
  __shared__ unsigned short flds[256 * 128];   // 64 KB; reused for out-transpose
  __shared__ float lsum[CC], lsq[CC];

  int tid = threadIdx.x;
  int bid = blockIdx.x;
  int b = bid / 49, tile = bid % 49;
  int p0 = tile * 256;

  if (tid < CC) { lsum[tid] = 0.f; lsq[tid] = 0.f; }

  const unsigned short* fb = feat + (long)b * CC * HWn + p0;
  int u   = (tid >> 3) & 7;        // c within group of 8
  int v   = tid & 7;               // pixel-group low
  int wv  = tid >> 6;              // wave 0..3
  int pgl = wv * 8 + v;            // pixel-group 0..31 (8 px each)

  bf16x8 vals[12];
#pragma unroll
  for (int s = 0; s < 12; ++s) {
    int c = s * 8 + u;
    vals[s] = *(const bf16x8*)(fb + (long)c * HWn + pgl * 8);
  }
#pragma unroll
  for (int s = 0; s < 12; ++s) {
#pragma unroll
    for (int e = 0; e < 8; ++e) {
      int pl = pgl * 8 + e;
      int kp = (pl ^ (pl >> 3)) & 7;
      flds[pl * 128 + ((s ^ kp) << 3) + u] = (unsigned short)vals[s][e];
    }
  }

  int l = tid & 63;
  int lm = l & 15, lg = l >> 4;
  bf16x8 a[6][3];
#pragma unroll
  for (int mt = 0; mt < 6; ++mt)
#pragma unroll
    for (int kk = 0; kk < 3; ++kk)
      a[mt][kk] = *(const bf16x8*)(wbf + (mt * 16 + lm) * CC + kk * 32 + lg * 8);

  __syncthreads();

  f32x4 acc[6][4];
#pragma unroll
  for (int mt = 0; mt < 6; ++mt)
#pragma unroll
    for (int j = 0; j < 4; ++j) acc[mt][j] = (f32x4){0.f, 0.f, 0.f, 0.f};

#pragma unroll
  for (int j = 0; j < 4; ++j) {
    int pl = (wv * 4 + j) * 16 + lm;
    int kp = (pl ^ (pl >> 3)) & 7;
#pragma unroll
    for (int kk = 0; kk < 3; ++kk) {
      bf16x8 bfrag = *(const bf16x8*)(&flds[pl * 128 + (((kk * 4 + lg) ^ kp) << 3)]);
#pragma unroll
      for (int mt = 0; mt < 6; ++mt)
        acc[mt][j] = __builtin_amdgcn_mfma_f32_16x16x32_bf16(a[mt][kk], bfrag, acc[mt][j], 0, 0, 0);
    }
  }

  __syncthreads();   // staging reads complete; reuse flds as [o][px'] u16

#pragma unroll
  for (int mt = 0; mt < 6; ++mt) {
#pragma unroll
    for (int r = 0; r < 4; ++r) {
      int o = mt * 16 + lg * 4 + r;          // (o>>2)&3 == lg
      float s = 0.f, q = 0.f;
#pragma unroll
      for (int j = 0; j < 4; ++j) {
        unsigned short h = f2bf(acc[mt][j][r]);
        float vv = bf2f(h);
        int px = (wv * 4 + j) * 16 + lm;
        flds[o * 256 + (px ^ (lg << 4))] = h;
        s += vv; q += vv * vv;
      }
      s += __shfl_xor(s, 1); q += __shfl_xor(q, 1);
      s += __shfl_xor(s, 2); q += __shfl_xor(q, 2);
      s += __shfl_xor(s, 4); q += __shfl_xor(q, 4);
      s += __shfl_xor(s, 8); q += __shfl_xor(q, 8);
      if (lm == 0) { atomicAdd(&lsum[o], s); atomicAdd(&lsq[o], q); }
    }
  }
  __syncthreads();

  unsigned short* mbase = mixed + (long)b * CC * HWn + p0;
  int o2 = tid >> 5;          // 0..7
  int pxg = tid & 31;         // 8-px group
#pragma unroll
  for (int i = 0; i < 12; ++i) {
    int o = i * 8 + o2;
    int key = (o >> 2) & 3;
    uint4 vv = *(const uint4*)(&flds[o * 256 + ((pxg * 8) ^ (key << 4))]);
    *(uint4*)(mbase + (long)o * HWn + pxg * 8) = vv;
  }

  if (tid < CC) atomicAdd(&ssum[tid], lsum[tid]);
  else if (tid < 2 * CC) atomicAdd(&ssq[tid - CC], lsq[tid - CC]);
}

__global__ void k_finalize(const float* __restrict__ ssum,
                           const float* __restrict__ ssq,
                           float* __restrict__ meanv,
                           float* __restrict__ rstdv) {
  int o = threadIdx.x;
  if (o < CC) {
    float m = ssum[o] * (1.0f / NPIX);
    float v = ssq[o] * (1.0f / NPIX) - m * m;
    meanv[o] = m;
    rstdv[o] = 1.0f / sqrtf(v + EPSf);
  }
}

// ---------------- BN (affine=False) + exact GELU, bf16 in / f32 out --------
__global__ __launch_bounds__(256) void k_bngelu(const unsigned short* __restrict__ mixed,
                                                const float* __restrict__ meanv,
                                                const float* __restrict__ rstdv,
                                                float* __restrict__ out) {
  long e = ((long)blockIdx.x * 256 + threadIdx.x) * 8;
  int o = (int)((e / HWn) % CC);       // 12544 % 8 == 0 -> same plane
  float m = meanv[o], r = rstdv[o];
  bf16x8 v = *(const bf16x8*)(mixed + e);
  float4 g0, g1;
  float z;
  z = (bf2f((unsigned short)v[0]) - m) * r; g0.x = 0.5f * z * (1.0f + erff(z * 0.70710678f));
  z = (bf2f((unsigned short)v[1]) - m) * r; g0.y = 0.5f * z * (1.0f + erff(z * 0.70710678f));
  z = (bf2f((unsigned short)v[2]) - m) * r; g0.z = 0.5f * z * (1.0f + erff(z * 0.70710678f));
  z = (bf2f((unsigned short)v[3]) - m) * r; g0.w = 0.5f * z * (1.0f + erff(z * 0.70710678f));
  z = (bf2f((unsigned short)v[4]) - m) * r; g1.x = 0.5f * z * (1.0f + erff(z * 0.70710678f));
  z = (bf2f((unsigned short)v[5]) - m) * r; g1.y = 0.5f * z * (1.0f + erff(z * 0.70710678f));
  z = (bf2f((unsigned short)v[6]) - m) * r; g1.z = 0.5f * z * (1.0f + erff(z * 0.70710678f));
  z = (bf2f((unsigned short)v[7]) - m) * r; g1.w = 0.5f * z * (1.0f + erff(z * 0.70710678f));
  *(float4*)(out + e)     = g0;
  *(float4*)(out + e + 4) = g1;
}

extern "C" void kernel_launch(void* const* d_in, const int* in_sizes, int n_in,
                              void* d_out, int out_size, void* d_ws, size_t ws_size,
                              hipStream_t stream) {
  const float* hk   = (const float*)d_in[0];   // local_hk [96,1,7,7]
  const float* x    = (const float*)d_in[1];   // x [32,96,112,112]
  const float* wmix = (const float*)d_in[2];   // w_mix [96,96]
  const float* bmix = (const float*)d_in[3];   // b_mix [96] (cancels in BN)
  (void)bmix;
  float* out = (float*)d_out;

  char* ws = (char*)d_ws;
  float* stats = (float*)ws;                           // sum,ssq,mean,rstd [96] each
  unsigned short* wbf     = (unsigned short*)(ws + 2048);            // 18432 B
  unsigned short* featbf  = (unsigned short*)(ws + 32768);           // 77,070,336 B
  unsigned short* mixedbf = (unsigned short*)(ws + 32768 + 77070336);

  hipMemsetAsync(stats, 0, 768, stream);       // zero sum+ssq each call

  k_prep<<<36, 256, 0, stream>>>(wmix, wbf);
  k_conv<<<6144, 256, 0, stream>>>(x, hk, featbf);
  k_mix<<<1568, 256, 0, stream>>>(featbf, wbf, mixedbf, stats, stats + 96);
  k_finalize<<<1, 128, 0, stream>>>(stats, stats + 96, stats + 192, stats + 288);
  k_bngelu<<<18816, 256, 0, stream>>>(mixedbf, stats + 192, stats + 288, out);
}

// Round 13
// 202.135 us; speedup vs baseline: 1.2207x; 1.0279x over previous
//
#include <hip/hip_runtime.h>
#include <cstdint>
#include <cstddef>

#define CC   96
#define BB   32
#define HHn  112
#define WWn  112
#define HWn  (HHn*WWn)        // 12544
#define NPIX (BB*HWn)         // 401408
#define EPSf 1e-5f

typedef __attribute__((ext_vector_type(8))) short bf16x8;
typedef __attribute__((ext_vector_type(4))) float f32x4;

__device__ inline unsigned short f2bf(float f) {      // RNE f32 -> bf16
  unsigned u = __float_as_uint(f);
  return (unsigned short)((u + 0x7FFFu + ((u >> 16) & 1u)) >> 16);
}
__device__ inline float bf2f(unsigned short h) {
  return __uint_as_float(((unsigned)h) << 16);
}
__device__ inline float bflo(unsigned u) { return __uint_as_float(u << 16); }
__device__ inline float bfhi(unsigned u) { return __uint_as_float(u & 0xffff0000u); }

// ---------------- w_mix f32[o][c] -> bf16[o][c] ----------------
__global__ __launch_bounds__(256) void k_prep(const float* __restrict__ w,
                                              unsigned short* __restrict__ wbf) {
  int i = blockIdx.x * 256 + threadIdx.x;
  if (i < CC * CC) wbf[i] = f2bf(w[i]);
}

// ---------------- depthwise 7x7 conv: bf16 LDS half-plane ----------------
// Block = half of one (b,c) plane (56 output rows), 256 threads.
// Stage rows r0-3..r0+58 (62) as bf16 (13.9 KB LDS).
// Item (224 active): q=tid/28 (7-row chunk), s=tid%28 (4-col strip).
// Per input row: 3x ds_read_b64 (12 bf16), unpack ONCE into win[12] regs,
// 7x7x4 FMA (f32 weights from SGPRs).
// launch_bounds(256,6): VGPR cap 85 so win[] stays register-cached —
// (256,8) squeezed VGPR to 32 and forced per-tap LDS re-reads (rd12, +22us).
__global__ __launch_bounds__(256, 6) void k_conv(const float* __restrict__ x,
                                                 const float* __restrict__ hk,
                                                 unsigned short* __restrict__ feat) {
  __shared__ unsigned short lpl[62 * 112];   // 13,888 B

  int tid = threadIdx.x;
  int bid = blockIdx.x;                                     // 6144
  int plane = __builtin_amdgcn_readfirstlane(bid >> 1);     // (b*C+c)
  int half  = __builtin_amdgcn_readfirstlane(bid & 1);
  int c = plane % CC;
  int r0 = half * 56;                   // first output row of this half
  const float* xp = x + (long)plane * HWn;
  unsigned short* fp = feat + (long)plane * HWn;

  // ---- stage 62 rows (row-clamped) f32 -> bf16: 1736 float4 ----
#pragma unroll
  for (int it = 0; it < 7; ++it) {
    int idx = it * 256 + tid;
    if (idx < 1736) {
      int rl = idx / 28;                // local row 0..61
      int c4 = idx % 28;
      int g = r0 - 3 + rl;
      int gc = g < 0 ? 0 : (g > HHn - 1 ? HHn - 1 : g);
      float4 v = *(const float4*)(xp + gc * WWn + c4 * 4);
      uint2 pk;
      pk.x = (unsigned)f2bf(v.x) | ((unsigned)f2bf(v.y) << 16);
      pk.y = (unsigned)f2bf(v.z) | ((unsigned)f2bf(v.w) << 16);
      *(uint2*)(&lpl[rl * WWn + c4 * 4]) = pk;
    }
  }

  // 49 weights -> SGPRs (uniform per block)
  float wk[49];
  const float* kc = hk + c * 49;
#pragma unroll
  for (int i = 0; i < 49; ++i)
    wk[i] = __uint_as_float(__builtin_amdgcn_readfirstlane(__float_as_uint(kc[i])));

  __syncthreads();
  if (tid >= 224) return;

  int q = tid / 28;                  // 7-row chunk 0..7
  int s = tid % 28;                  // 4-col strip
  int cb = s * 4;                    // window cols cb-3..cb+6
  int qb_l = q * 7;                  // local output-row base (LDS row qb_l+rr)
  bool aok0 = (s > 0);
  bool cok0 = (s < 27);
  int e0 = aok0 ? cb - 4 : 0;        // first b64 elem offset (clamped)
  int e2 = cok0 ? cb + 4 : cb;       // last  b64 elem offset (clamped)

  float acc[7][4];
#pragma unroll
  for (int i = 0; i < 7; ++i)
#pragma unroll
    for (int j = 0; j < 4; ++j) acc[i][j] = 0.f;

#pragma unroll
  for (int rr = 0; rr < 13; ++rr) {       // input rows (global) r0+qb_l+rr-3
    int g = r0 + qb_l + rr - 3;
    bool vok = ((unsigned)g < (unsigned)HHn);
    const unsigned short* rowp = &lpl[(qb_l + rr) * WWn];
    uint2 U0 = *(const uint2*)(rowp + e0);   // cols cb-4..cb-1
    uint2 U1 = *(const uint2*)(rowp + cb);   // cols cb  ..cb+3
    uint2 U2 = *(const uint2*)(rowp + e2);   // cols cb+4..cb+7
    if (!(vok && aok0)) { U0.x = 0u; U0.y = 0u; }
    if (!vok)           { U1.x = 0u; U1.y = 0u; }
    if (!(vok && cok0)) { U2.x = 0u; U2.y = 0u; }

    float win[12];                    // win[w] = x col cb-4+w
    win[0]  = bflo(U0.x); win[1]  = bfhi(U0.x);
    win[2]  = bflo(U0.y); win[3]  = bfhi(U0.y);
    win[4]  = bflo(U1.x); win[5]  = bfhi(U1.x);
    win[6]  = bflo(U1.y); win[7]  = bfhi(U1.y);
    win[8]  = bflo(U2.x); win[9]  = bfhi(U2.x);
    win[10] = bflo(U2.y); win[11] = bfhi(U2.y);

    // input row rr feeds output slot = rr-kh (compile-time indices)
#pragma unroll
    for (int kh = 0; kh < 7; ++kh) {
      if (rr >= kh && rr - kh <= 6) {
        const int slot = rr - kh;
#pragma unroll
        for (int kw = 0; kw < 7; ++kw) {
          float wv = wk[kh * 7 + kw];
#pragma unroll
          for (int j = 0; j < 4; ++j)
            acc[slot][j] = fmaf(win[1 + kw + j], wv, acc[slot][j]);
        }
      }
    }

    if (rr >= 6) {                        // output row complete
      const int slot = rr - 6;
      unsigned short* orow = fp + (r0 + qb_l + slot) * WWn + cb;
      uint2 pk;
      pk.x = (unsigned)f2bf(acc[slot][0]) | ((unsigned)f2bf(acc[slot][1]) << 16);
      pk.y = (unsigned)f2bf(acc[slot][2]) | ((unsigned)f2bf(acc[slot][3]) << 16);
      *(uint2*)orow = pk;
    }
  }
}

// ------- MFMA 1x1 mix (bf16) + fused BN stats, 256 px/block -------
__global__ __launch_bounds__(256, 2) void k_mix(const unsigned short* __restrict__ feat,
                                                const unsigned short* __restrict__ wbf,
                                                unsigned short* __restrict__ mixed,
                                                float* __restrict__ ssum,
                                                float* __restrict__ ssq) {
  __shared__ unsigned short flds[256 * 128];   // 64 KB; reused for out-transpose
  __shared__ float lsum[CC], lsq[CC];

  int tid = threadIdx.x;
  int bid = blockIdx.x;
  int b = bid / 49, tile = bid % 49;
  int p0 = tile * 256;

  if (tid < CC) { lsum[tid] = 0.f; lsq[tid] = 0.f; }

  const unsigned short* fb = feat + (long)b * CC * HWn + p0;
  int u   = (tid >> 3) & 7;        // c within group of 8
  int v   = tid & 7;               // pixel-group low
  int wv  = tid >> 6;              // wave 0..3
  int pgl = wv * 8 + v;            // pixel-group 0..31 (8 px each)

  bf16x8 vals[12];
#pragma unroll
  for (int s = 0; s < 12; ++s) {
    int c = s * 8 + u;
    vals[s] = *(const bf16x8*)(fb + (long)c * HWn + pgl * 8);
  }
#pragma unroll
  for (int s = 0; s < 12; ++s) {
#pragma unroll
    for (int e = 0; e < 8; ++e) {
      int pl = pgl * 8 + e;
      int kp = (pl ^ (pl >> 3)) & 7;
      flds[pl * 128 + ((s ^ kp) << 3) + u] = (unsigned short)vals[s][e];
    }
  }

  int l = tid & 63;
  int lm = l & 15, lg = l >> 4;
  bf16x8 a[6][3];
#pragma unroll
  for (int mt = 0; mt < 6; ++mt)
#pragma unroll
    for (int kk = 0; kk < 3; ++kk)
      a[mt][kk] = *(const bf16x8*)(wbf + (mt * 16 + lm) * CC + kk * 32 + lg * 8);

  __syncthreads();

  f32x4 acc[6][4];
#pragma unroll
  for (int mt = 0; mt < 6; ++mt)
#pragma unroll
    for (int j = 0; j < 4; ++j) acc[mt][j] = (f32x4){0.f, 0.f, 0.f, 0.f};

#pragma unroll
  for (int j = 0; j < 4; ++j) {
    int pl = (wv * 4 + j) * 16 + lm;
    int kp = (pl ^ (pl >> 3)) & 7;
#pragma unroll
    for (int kk = 0; kk < 3; ++kk) {
      bf16x8 bfrag = *(const bf16x8*)(&flds[pl * 128 + (((kk * 4 + lg) ^ kp) << 3)]);
#pragma unroll
      for (int mt = 0; mt < 6; ++mt)
        acc[mt][j] = __builtin_amdgcn_mfma_f32_16x16x32_bf16(a[mt][kk], bfrag, acc[mt][j], 0, 0, 0);
    }
  }

  __syncthreads();   // staging reads complete; reuse flds as [o][px'] u16

#pragma unroll
  for (int mt = 0; mt < 6; ++mt) {
#pragma unroll
    for (int r = 0; r < 4; ++r) {
      int o = mt * 16 + lg * 4 + r;          // (o>>2)&3 == lg
      float s = 0.f, q = 0.f;
#pragma unroll
      for (int j = 0; j < 4; ++j) {
        unsigned short h = f2bf(acc[mt][j][r]);
        float vv = bf2f(h);
        int px = (wv * 4 + j) * 16 + lm;
        flds[o * 256 + (px ^ (lg << 4))] = h;
        s += vv; q += vv * vv;
      }
      s += __shfl_xor(s, 1); q += __shfl_xor(q, 1);
      s += __shfl_xor(s, 2); q += __shfl_xor(q, 2);
      s += __shfl_xor(s, 4); q += __shfl_xor(q, 4);
      s += __shfl_xor(s, 8); q += __shfl_xor(q, 8);
      if (lm == 0) { atomicAdd(&lsum[o], s); atomicAdd(&lsq[o], q); }
    }
  }
  __syncthreads();

  unsigned short* mbase = mixed + (long)b * CC * HWn + p0;
  int o2 = tid >> 5;          // 0..7
  int pxg = tid & 31;         // 8-px group
#pragma unroll
  for (int i = 0; i < 12; ++i) {
    int o = i * 8 + o2;
    int key = (o >> 2) & 3;
    uint4 vv = *(const uint4*)(&flds[o * 256 + ((pxg * 8) ^ (key << 4))]);
    *(uint4*)(mbase + (long)o * HWn + pxg * 8) = vv;
  }

  if (tid < CC) atomicAdd(&ssum[tid], lsum[tid]);
  else if (tid < 2 * CC) atomicAdd(&ssq[tid - CC], lsq[tid - CC]);
}

__global__ void k_finalize(const float* __restrict__ ssum,
                           const float* __restrict__ ssq,
                           float* __restrict__ meanv,
                           float* __restrict__ rstdv) {
  int o = threadIdx.x;
  if (o < CC) {
    float m = ssum[o] * (1.0f / NPIX);
    float v = ssq[o] * (1.0f / NPIX) - m * m;
    meanv[o] = m;
    rstdv[o] = 1.0f / sqrtf(v + EPSf);
  }
}

// ---------------- BN (affine=False) + exact GELU, bf16 in / f32 out --------
__global__ __launch_bounds__(256) void k_bngelu(const unsigned short* __restrict__ mixed,
                                                const float* __restrict__ meanv,
                                                const float* __restrict__ rstdv,
                                                float* __restrict__ out) {
  long e = ((long)blockIdx.x * 256 + threadIdx.x) * 8;
  int o = (int)((e / HWn) % CC);       // 12544 % 8 == 0 -> same plane
  float m = meanv[o], r = rstdv[o];
  bf16x8 v = *(const bf16x8*)(mixed + e);
  float4 g0, g1;
  float z;
  z = (bf2f((unsigned short)v[0]) - m) * r; g0.x = 0.5f * z * (1.0f + erff(z * 0.70710678f));
  z = (bf2f((unsigned short)v[1]) - m) * r; g0.y = 0.5f * z * (1.0f + erff(z * 0.70710678f));
  z = (bf2f((unsigned short)v[2]) - m) * r; g0.z = 0.5f * z * (1.0f + erff(z * 0.70710678f));
  z = (bf2f((unsigned short)v[3]) - m) * r; g0.w = 0.5f * z * (1.0f + erff(z * 0.70710678f));
  z = (bf2f((unsigned short)v[4]) - m) * r; g1.x = 0.5f * z * (1.0f + erff(z * 0.70710678f));
  z = (bf2f((unsigned short)v[5]) - m) * r; g1.y = 0.5f * z * (1.0f + erff(z * 0.70710678f));
  z = (bf2f((unsigned short)v[6]) - m) * r; g1.z = 0.5f * z * (1.0f + erff(z * 0.70710678f));
  z = (bf2f((unsigned short)v[7]) - m) * r; g1.w = 0.5f * z * (1.0f + erff(z * 0.70710678f));
  *(float4*)(out + e)     = g0;
  *(float4*)(out + e + 4) = g1;
}

extern "C" void kernel_launch(void* const* d_in, const int* in_sizes, int n_in,
                              void* d_out, int out_size, void* d_ws, size_t ws_size,
                              hipStream_t stream) {
  const float* hk   = (const float*)d_in[0];   // local_hk [96,1,7,7]
  const float* x    = (const float*)d_in[1];   // x [32,96,112,112]
  const float* wmix = (const float*)d_in[2];   // w_mix [96,96]
  const float* bmix = (const float*)d_in[3];   // b_mix [96] (cancels in BN)
  (void)bmix;
  float* out = (float*)d_out;

  char* ws = (char*)d_ws;
  float* stats = (float*)ws;                           // sum,ssq,mean,rstd [96] each
  unsigned short* wbf     = (unsigned short*)(ws + 2048);            // 18432 B
  unsigned short* featbf  = (unsigned short*)(ws + 32768);           // 77,070,336 B
  unsigned short* mixedbf = (unsigned short*)(ws + 32768 + 77070336);

  hipMemsetAsync(stats, 0, 768, stream);       // zero sum+ssq each call

  k_prep<<<36, 256, 0, stream>>>(wmix, wbf);
  k_conv<<<6144, 256, 0, stream>>>(x, hk, featbf);
  k_mix<<<1568, 256, 0, stream>>>(featbf, wbf, mixedbf, stats, stats + 96);
  k_finalize<<<1, 128, 0, stream>>>(stats, stats + 96, stats + 192, stats + 288);
  k_bngelu<<<18816, 256, 0, stream>>>(mixedbf, stats + 192, stats + 288, out);
}

// Round 14
// 182.850 us; speedup vs baseline: 1.3495x; 1.1055x over previous
//
#include <hip/hip_runtime.h>
#include <hip/hip_bf16.h>
#include <cstdint>
#include <cstddef>

#define CC   96
#define BB   32
#define HHn  112
#define WWn  112
#define HWn  (HHn*WWn)        // 12544
#define NPIX (BB*HWn)         // 401408
#define EPSf 1e-5f

typedef __attribute__((ext_vector_type(8))) short bf16x8;
typedef __attribute__((ext_vector_type(4))) float f32x4;

__device__ inline unsigned short f2bf(float f) {      // RNE f32 -> bf16 (bit math)
  unsigned u = __float_as_uint(f);
  return (unsigned short)((u + 0x7FFFu + ((u >> 16) & 1u)) >> 16);
}
__device__ inline float bf2f(unsigned short h) {
  return __uint_as_float(((unsigned)h) << 16);
}
__device__ inline float bflo(unsigned u) { return __uint_as_float(u << 16); }
__device__ inline float bfhi(unsigned u) { return __uint_as_float(u & 0xffff0000u); }
__device__ inline unsigned pkbf(float a, float b) {   // v_cvt_pk_bf16_f32 (RNE)
  __hip_bfloat162 h = __float22bfloat162_rn(float2{a, b});
  return *reinterpret_cast<unsigned*>(&h);
}

// ---------------- w_mix f32[o][c] -> bf16[o][c] ----------------
__global__ __launch_bounds__(256) void k_prep(const float* __restrict__ w,
                                              unsigned short* __restrict__ wbf) {
  int i = blockIdx.x * 256 + threadIdx.x;
  if (i < CC * CC) wbf[i] = f2bf(w[i]);
}

// ---------------- depthwise 7x7 conv: bf16 LDS FULL plane ----------------
// Block = one (b,c) plane, 512 threads; plane staged as bf16 (25 KB LDS,
// zero halo waste). 448 active items: q=tid/28 (7-row chunk), s=tid%28
// (4-col strip). Per input row: 3x ds_read_b64, unpack once to win[12],
// 7x7x4 FMA vs SGPR weights. Packs via v_cvt_pk_bf16_f32.
// Occupancy goal: VGPR<=64 -> 4 blocks x 8 waves = 32 waves/CU.
__global__ __launch_bounds__(512, 4) void k_conv(const float* __restrict__ x,
                                                 const float* __restrict__ hk,
                                                 unsigned short* __restrict__ feat) {
  __shared__ unsigned short lpl[HWn];   // 25,088 B

  int tid = threadIdx.x;
  int plane = __builtin_amdgcn_readfirstlane(blockIdx.x);   // (b*C+c)
  int c = plane % CC;
  const float* xp = x + (long)plane * HWn;
  unsigned short* fp = feat + (long)plane * HWn;

  // ---- stage full plane f32 -> bf16: 3136 float4 = 6*512 + 64 ----
#pragma unroll
  for (int it = 0; it < 6; ++it) {
    int idx = it * 512 + tid;
    float4 v = *(const float4*)(xp + idx * 4);
    uint2 pk;
    pk.x = pkbf(v.x, v.y);
    pk.y = pkbf(v.z, v.w);
    *(uint2*)(&lpl[idx * 4]) = pk;
  }
  if (tid < 64) {
    int idx = 3072 + tid;
    float4 v = *(const float4*)(xp + idx * 4);
    uint2 pk;
    pk.x = pkbf(v.x, v.y);
    pk.y = pkbf(v.z, v.w);
    *(uint2*)(&lpl[idx * 4]) = pk;
  }

  // 49 weights -> SGPRs (uniform per block)
  float wk[49];
  const float* kc = hk + c * 49;
#pragma unroll
  for (int i = 0; i < 49; ++i)
    wk[i] = __uint_as_float(__builtin_amdgcn_readfirstlane(__float_as_uint(kc[i])));

  __syncthreads();
  if (tid >= 448) return;            // no barriers after this point

  int q = tid / 28;                  // 7-row chunk 0..15
  int s = tid % 28;                  // 4-col strip
  int cb = s * 4;                    // window cols cb-3..cb+6
  int qb = q * 7;                    // first output row of this item
  bool aok0 = (s > 0);
  bool cok0 = (s < 27);
  int e0 = aok0 ? cb - 4 : 0;        // first b64 elem offset (clamped)
  int e2 = cok0 ? cb + 4 : cb;       // last  b64 elem offset (clamped)

  float acc[7][4];
#pragma unroll
  for (int i = 0; i < 7; ++i)
#pragma unroll
    for (int j = 0; j < 4; ++j) acc[i][j] = 0.f;

#pragma unroll
  for (int rr = 0; rr < 13; ++rr) {       // input rows qb+rr-3
    int g = qb + rr - 3;
    bool vok = ((unsigned)g < (unsigned)HHn);
    int gc = g < 0 ? 0 : (g > HHn - 1 ? HHn - 1 : g);
    const unsigned short* rowp = &lpl[gc * WWn];
    uint2 U0 = *(const uint2*)(rowp + e0);   // cols cb-4..cb-1
    uint2 U1 = *(const uint2*)(rowp + cb);   // cols cb  ..cb+3
    uint2 U2 = *(const uint2*)(rowp + e2);   // cols cb+4..cb+7
    if (!(vok && aok0)) { U0.x = 0u; U0.y = 0u; }
    if (!vok)           { U1.x = 0u; U1.y = 0u; }
    if (!(vok && cok0)) { U2.x = 0u; U2.y = 0u; }

    float win[12];                    // win[w] = x col cb-4+w
    win[0]  = bflo(U0.x); win[1]  = bfhi(U0.x);
    win[2]  = bflo(U0.y); win[3]  = bfhi(U0.y);
    win[4]  = bflo(U1.x); win[5]  = bfhi(U1.x);
    win[6]  = bflo(U1.y); win[7]  = bfhi(U1.y);
    win[8]  = bflo(U2.x); win[9]  = bfhi(U2.x);
    win[10] = bflo(U2.y); win[11] = bfhi(U2.y);

    // input row rr feeds output slot = rr-kh (compile-time indices)
#pragma unroll
    for (int kh = 0; kh < 7; ++kh) {
      if (rr >= kh && rr - kh <= 6) {
        const int slot = rr - kh;
#pragma unroll
        for (int kw = 0; kw < 7; ++kw) {
          float wv = wk[kh * 7 + kw];
#pragma unroll
          for (int j = 0; j < 4; ++j)
            acc[slot][j] = fmaf(win[1 + kw + j], wv, acc[slot][j]);
        }
      }
    }

    if (rr >= 6) {                        // output row qb+rr-6 complete
      const int slot = rr - 6;
      unsigned short* orow = fp + (qb + slot) * WWn + cb;
      uint2 pk;
      pk.x = pkbf(acc[slot][0], acc[slot][1]);
      pk.y = pkbf(acc[slot][2], acc[slot][3]);
      *(uint2*)orow = pk;
    }
  }
}

// ------- MFMA 1x1 mix (bf16) + fused BN stats, 256 px/block -------
__global__ __launch_bounds__(256, 2) void k_mix(const unsigned short* __restrict__ feat,
                                                const unsigned short* __restrict__ wbf,
                                                unsigned short* __restrict__ mixed,
                                                float* __restrict__ ssum,
                                                float* __restrict__ ssq) {
  __shared__ unsigned short flds[256 * 128];   // 64 KB; reused for out-transpose
  __shared__ float lsum[CC], lsq[CC];

  int tid = threadIdx.x;
  int bid = blockIdx.x;
  int b = bid / 49, tile = bid % 49;
  int p0 = tile * 256;

  if (tid < CC) { lsum[tid] = 0.f; lsq[tid] = 0.f; }

  const unsigned short* fb = feat + (long)b * CC * HWn + p0;
  int u   = (tid >> 3) & 7;        // c within group of 8
  int v   = tid & 7;               // pixel-group low
  int wv  = tid >> 6;              // wave 0..3
  int pgl = wv * 8 + v;            // pixel-group 0..31 (8 px each)

  bf16x8 vals[12];
#pragma unroll
  for (int s = 0; s < 12; ++s) {
    int c = s * 8 + u;
    vals[s] = *(const bf16x8*)(fb + (long)c * HWn + pgl * 8);
  }
#pragma unroll
  for (int s = 0; s < 12; ++s) {
#pragma unroll
    for (int e = 0; e < 8; ++e) {
      int pl = pgl * 8 + e;
      int kp = (pl ^ (pl >> 3)) & 7;
      flds[pl * 128 + ((s ^ kp) << 3) + u] = (unsigned short)vals[s][e];
    }
  }

  int l = tid & 63;
  int lm = l & 15, lg = l >> 4;
  bf16x8 a[6][3];
#pragma unroll
  for (int mt = 0; mt < 6; ++mt)
#pragma unroll
    for (int kk = 0; kk < 3; ++kk)
      a[mt][kk] = *(const bf16x8*)(wbf + (mt * 16 + lm) * CC + kk * 32 + lg * 8);

  __syncthreads();

  f32x4 acc[6][4];
#pragma unroll
  for (int mt = 0; mt < 6; ++mt)
#pragma unroll
    for (int j = 0; j < 4; ++j) acc[mt][j] = (f32x4){0.f, 0.f, 0.f, 0.f};

#pragma unroll
  for (int j = 0; j < 4; ++j) {
    int pl = (wv * 4 + j) * 16 + lm;
    int kp = (pl ^ (pl >> 3)) & 7;
#pragma unroll
    for (int kk = 0; kk < 3; ++kk) {
      bf16x8 bfrag = *(const bf16x8*)(&flds[pl * 128 + (((kk * 4 + lg) ^ kp) << 3)]);
#pragma unroll
      for (int mt = 0; mt < 6; ++mt)
        acc[mt][j] = __builtin_amdgcn_mfma_f32_16x16x32_bf16(a[mt][kk], bfrag, acc[mt][j], 0, 0, 0);
    }
  }

  __syncthreads();   // staging reads complete; reuse flds as [o][px'] u16

#pragma unroll
  for (int mt = 0; mt < 6; ++mt) {
#pragma unroll
    for (int r = 0; r < 4; ++r) {
      int o = mt * 16 + lg * 4 + r;          // (o>>2)&3 == lg
      float s = 0.f, q = 0.f;
#pragma unroll
      for (int j = 0; j < 4; ++j) {
        unsigned short h = f2bf(acc[mt][j][r]);
        float vv = bf2f(h);
        int px = (wv * 4 + j) * 16 + lm;
        flds[o * 256 + (px ^ (lg << 4))] = h;
        s += vv; q += vv * vv;
      }
      s += __shfl_xor(s, 1); q += __shfl_xor(q, 1);
      s += __shfl_xor(s, 2); q += __shfl_xor(q, 2);
      s += __shfl_xor(s, 4); q += __shfl_xor(q, 4);
      s += __shfl_xor(s, 8); q += __shfl_xor(q, 8);
      if (lm == 0) { atomicAdd(&lsum[o], s); atomicAdd(&lsq[o], q); }
    }
  }
  __syncthreads();

  unsigned short* mbase = mixed + (long)b * CC * HWn + p0;
  int o2 = tid >> 5;          // 0..7
  int pxg = tid & 31;         // 8-px group
#pragma unroll
  for (int i = 0; i < 12; ++i) {
    int o = i * 8 + o2;
    int key = (o >> 2) & 3;
    uint4 vv = *(const uint4*)(&flds[o * 256 + ((pxg * 8) ^ (key << 4))]);
    *(uint4*)(mbase + (long)o * HWn + pxg * 8) = vv;
  }

  if (tid < CC) atomicAdd(&ssum[tid], lsum[tid]);
  else if (tid < 2 * CC) atomicAdd(&ssq[tid - CC], lsq[tid - CC]);
}

__global__ void k_finalize(const float* __restrict__ ssum,
                           const float* __restrict__ ssq,
                           float* __restrict__ meanv,
                           float* __restrict__ rstdv) {
  int o = threadIdx.x;
  if (o < CC) {
    float m = ssum[o] * (1.0f / NPIX);
    float v = ssq[o] * (1.0f / NPIX) - m * m;
    meanv[o] = m;
    rstdv[o] = 1.0f / sqrtf(v + EPSf);
  }
}

// ---------------- BN (affine=False) + exact GELU, bf16 in / f32 out --------
__global__ __launch_bounds__(256) void k_bngelu(const unsigned short* __restrict__ mixed,
                                                const float* __restrict__ meanv,
                                                const float* __restrict__ rstdv,
                                                float* __restrict__ out) {
  long e = ((long)blockIdx.x * 256 + threadIdx.x) * 8;
  int o = (int)((e / HWn) % CC);       // 12544 % 8 == 0 -> same plane
  float m = meanv[o], r = rstdv[o];
  bf16x8 v = *(const bf16x8*)(mixed + e);
  float4 g0, g1;
  float z;
  z = (bf2f((unsigned short)v[0]) - m) * r; g0.x = 0.5f * z * (1.0f + erff(z * 0.70710678f));
  z = (bf2f((unsigned short)v[1]) - m) * r; g0.y = 0.5f * z * (1.0f + erff(z * 0.70710678f));
  z = (bf2f((unsigned short)v[2]) - m) * r; g0.z = 0.5f * z * (1.0f + erff(z * 0.70710678f));
  z = (bf2f((unsigned short)v[3]) - m) * r; g0.w = 0.5f * z * (1.0f + erff(z * 0.70710678f));
  z = (bf2f((unsigned short)v[4]) - m) * r; g1.x = 0.5f * z * (1.0f + erff(z * 0.70710678f));
  z = (bf2f((unsigned short)v[5]) - m) * r; g1.y = 0.5f * z * (1.0f + erff(z * 0.70710678f));
  z = (bf2f((unsigned short)v[6]) - m) * r; g1.z = 0.5f * z * (1.0f + erff(z * 0.70710678f));
  z = (bf2f((unsigned short)v[7]) - m) * r; g1.w = 0.5f * z * (1.0f + erff(z * 0.70710678f));
  *(float4*)(out + e)     = g0;
  *(float4*)(out + e + 4) = g1;
}

extern "C" void kernel_launch(void* const* d_in, const int* in_sizes, int n_in,
                              void* d_out, int out_size, void* d_ws, size_t ws_size,
                              hipStream_t stream) {
  const float* hk   = (const float*)d_in[0];   // local_hk [96,1,7,7]
  const float* x    = (const float*)d_in[1];   // x [32,96,112,112]
  const float* wmix = (const float*)d_in[2];   // w_mix [96,96]
  const float* bmix = (const float*)d_in[3];   // b_mix [96] (cancels in BN)
  (void)bmix;
  float* out = (float*)d_out;

  char* ws = (char*)d_ws;
  float* stats = (float*)ws;                           // sum,ssq,mean,rstd [96] each
  unsigned short* wbf     = (unsigned short*)(ws + 2048);            // 18432 B
  unsigned short* featbf  = (unsigned short*)(ws + 32768);           // 77,070,336 B
  unsigned short* mixedbf = (unsigned short*)(ws + 32768 + 77070336);

  hipMemsetAsync(stats, 0, 768, stream);       // zero sum+ssq each call

  k_prep<<<36, 256, 0, stream>>>(wmix, wbf);
  k_conv<<<3072, 512, 0, stream>>>(x, hk, featbf);
  k_mix<<<1568, 256, 0, stream>>>(featbf, wbf, mixedbf, stats, stats + 96);
  k_finalize<<<1, 128, 0, stream>>>(stats, stats + 96, stats + 192, stats + 288);
  k_bngelu<<<18816, 256, 0, stream>>>(mixedbf, stats + 192, stats + 288, out);
}